// Round 5
// baseline (301.798 us; speedup 1.0000x reference)
//
#include <hip/hip_runtime.h>
#include <hip/hip_bf16.h>

// WindowAttention3D: 3136 windows, N=64 tokens, C=128, H=4 heads, hd=32.
// One block per window, 4 waves, wave = head.
// v5 = v4 + latency/occupancy attack:
//   - halved K/Q/V staging (32-token halves, same-wave in-order DS) ->
//     per-wave buf 1280 el, LDS 27648 B -> 5 blocks/CU cap (20 waves).
//     launch_bounds stays (256,4): compiler reg budget 128; HW packs 5
//     blocks if natural VGPR <= ~102 (forcing (256,5) spilled in v2).
//   - swapped K/Q GEMMs: mfma(W, X) -> K^T in C-layout -> packed bf16x4
//     transposed stores (32 ds_write_b16 -> 8 ds_write_b64 per phase),
//     bias as f32x4 per tile.
//   - transposed bias tables: rpe_t [h][col][row] (64KB, always) and
//     mask_t [w][col][row] (6.4MB, only if ws_size permits; template
//     fallback keeps v4 scalar mask loads). Per band: 8 f32x4 loads vs 32
//     scalar; band0 issued before barrier 2, band mt+1 prefetched under PV.
//
// LDS map (bf16 elements):
//   [0, 8704)        xs  [64][136]  x staging -- later O staging [64][136]
//   [8704, 13824)    per-wave buf 1280 el:
//                      K/Q: [32][40] half-buffer (token halves)
//                      V:   [32][40] half-buffer (token halves)
//                      P:   [16][72] (vf already in regs)

typedef __bf16 bf16x8 __attribute__((ext_vector_type(8)));
typedef __bf16 bf16x4 __attribute__((ext_vector_type(4)));
typedef float f32x4 __attribute__((ext_vector_type(4)));

#define NWMASK 392
#define SCALE 0.17677669529663687f  // 1/sqrt(32)

// ---------------- prep: weights->bf16, rpe_t gather, mask transpose ----------------
// blocks 0..319: elementwise (wqkv, wproj, rpe_t). blocks 320..711: mask_t
// (one 64x64 tile per block via LDS), skipped when do_mask==0.
__global__ void prep(const float* __restrict__ qkv_w, const float* __restrict__ proj_w,
                     const float* __restrict__ tbl, const int* __restrict__ ridx,
                     __bf16* __restrict__ wqkv, __bf16* __restrict__ wproj,
                     float* __restrict__ rpe_t,
                     const float* __restrict__ mask, float* __restrict__ mask_t,
                     int do_mask) {
    __shared__ float t[64][65];
    if (blockIdx.x < 320) {
        int i = blockIdx.x * 256 + threadIdx.x;
        if (i < 49152) {
            wqkv[i] = (__bf16)qkv_w[i];                  // [384][128]
        } else if (i < 65536) {
            int j = i - 49152;  wproj[j] = (__bf16)proj_w[j];   // [128][128]
        } else {
            int j = i - 65536;                           // rpe_t [4][col 64][row 64]
            rpe_t[j] = tbl[ridx[(j & 63) * 64 + ((j >> 6) & 63)] * 4 + (j >> 12)];
        }
    } else {
        if (!do_mask) return;
        const int w = blockIdx.x - 320;                  // [392] windows
        const int c = threadIdx.x & 63, rb = threadIdx.x >> 6;
        const float* src = mask + (size_t)w * 4096;
        #pragma unroll
        for (int i = 0; i < 16; ++i) { int r = rb * 16 + i; t[r][c] = src[r * 64 + c]; }
        __syncthreads();
        float* dst = mask_t + (size_t)w * 4096;          // [w][col][row]
        #pragma unroll
        for (int i = 0; i < 16; ++i) { int r = rb * 16 + i; dst[r * 64 + c] = t[c][r]; }
    }
}

// ---------------- main fused kernel ----------------
// TB: maskp is transposed [w][col][row]; else original [w][row][col].
template<bool TB>
__global__ __launch_bounds__(256, 4) void wattn_main(
    const float* __restrict__ x, const float* __restrict__ maskp,
    const float* __restrict__ qkv_b, const float* __restrict__ proj_b,
    const __bf16* __restrict__ wqkv, const __bf16* __restrict__ wproj,
    const float* __restrict__ rpe_t, float* __restrict__ out)
{
    __shared__ __align__(16) __bf16 smem[13824];   // 27648 B -> 5 blocks/CU
    const int win  = blockIdx.x;
    const int tid  = threadIdx.x;
    const int h    = tid >> 6;        // wave id = head (and token band in proj)
    const int lane = tid & 63;
    const int quad = lane >> 4;
    const int l16  = lane & 15;

    __bf16* const xs  = smem;                     // [64][136]; O staging later
    __bf16* const buf = smem + 8704 + h * 1280;   // wave-private

    // ---- Phase 0: cooperative x staging, fp32 -> bf16, fully coalesced ----
    {
        const float* xb = x + (size_t)win * 8192;
        #pragma unroll
        for (int i = 0; i < 2; ++i) {
            const int row  = h * 16 + (lane >> 3) + i * 8;
            const int colg = (lane & 7) * 16;
            const float* xp = xb + row * 128 + colg;
            float4 a0 = *(const float4*)(xp);
            float4 a1 = *(const float4*)(xp + 4);
            float4 a2 = *(const float4*)(xp + 8);
            float4 a3 = *(const float4*)(xp + 12);
            bf16x8 t0, t1;
            t0[0]=(__bf16)a0.x; t0[1]=(__bf16)a0.y; t0[2]=(__bf16)a0.z; t0[3]=(__bf16)a0.w;
            t0[4]=(__bf16)a1.x; t0[5]=(__bf16)a1.y; t0[6]=(__bf16)a1.z; t0[7]=(__bf16)a1.w;
            t1[0]=(__bf16)a2.x; t1[1]=(__bf16)a2.y; t1[2]=(__bf16)a2.z; t1[3]=(__bf16)a2.w;
            t1[4]=(__bf16)a3.x; t1[5]=(__bf16)a3.y; t1[6]=(__bf16)a3.z; t1[7]=(__bf16)a3.w;
            *(bf16x8*)(xs + row * 136 + colg)     = t0;
            *(bf16x8*)(xs + row * 136 + colg + 8) = t1;
        }
    }

    // K-phase weights issued BEFORE barrier 1 (latency under barrier wait).
    bf16x8 kwf[2][4]; f32x4 kb4[2];
    #pragma unroll
    for (int nt = 0; nt < 2; ++nt) {
        const int ng = 128 + h * 32 + nt * 16 + l16;
        kb4[nt] = *(const f32x4*)(qkv_b + 128 + h * 32 + nt * 16 + quad * 4);
        #pragma unroll
        for (int kt = 0; kt < 4; ++kt)
            kwf[nt][kt] = *(const bf16x8*)(wqkv + ng * 128 + kt * 32 + quad * 8);
    }
    __syncthreads();   // barrier 1: xs ready

    bf16x8 kf[4], qf[4], vf[2][2];

    // ---- K phase (swapped): C = Wk * X^T -> K^T in C-layout; packed bf16x4
    //      transposed store -> [token][feat] half-buffer [32][40] ----
    #pragma unroll
    for (int half = 0; half < 2; ++half) {
        #pragma unroll
        for (int m2 = 0; m2 < 2; ++m2) {
            const int mt = half * 2 + m2;
            bf16x8 af[4];
            #pragma unroll
            for (int kt = 0; kt < 4; ++kt)
                af[kt] = *(const bf16x8*)(xs + (mt * 16 + l16) * 136 + kt * 32 + quad * 8);
            #pragma unroll
            for (int nt = 0; nt < 2; ++nt) {
                f32x4 acc = {0.f, 0.f, 0.f, 0.f};
                #pragma unroll
                for (int kt = 0; kt < 4; ++kt)
                    acc = __builtin_amdgcn_mfma_f32_16x16x32_bf16(kwf[nt][kt], af[kt], acc, 0, 0, 0);
                bf16x4 pk;
                #pragma unroll
                for (int r = 0; r < 4; ++r) pk[r] = (__bf16)(acc[r] + kb4[nt][r]);
                *(bf16x4*)(buf + (m2 * 16 + l16) * 40 + nt * 16 + quad * 4) = pk;
            }
        }
        kf[half * 2 + 0] = *(const bf16x8*)(buf + l16 * 40 + quad * 8);
        kf[half * 2 + 1] = *(const bf16x8*)(buf + (16 + l16) * 40 + quad * 8);
    }

    // ---- Q phase (swapped, pre-scaled), same structure ----
    {
        bf16x8 qwf[2][4]; f32x4 qb4[2];
        #pragma unroll
        for (int nt = 0; nt < 2; ++nt) {
            const int ng = h * 32 + nt * 16 + l16;
            qb4[nt] = *(const f32x4*)(qkv_b + h * 32 + nt * 16 + quad * 4);
            #pragma unroll
            for (int kt = 0; kt < 4; ++kt)
                qwf[nt][kt] = *(const bf16x8*)(wqkv + ng * 128 + kt * 32 + quad * 8);
        }
        #pragma unroll
        for (int half = 0; half < 2; ++half) {
            #pragma unroll
            for (int m2 = 0; m2 < 2; ++m2) {
                const int mt = half * 2 + m2;
                bf16x8 af[4];
                #pragma unroll
                for (int kt = 0; kt < 4; ++kt)
                    af[kt] = *(const bf16x8*)(xs + (mt * 16 + l16) * 136 + kt * 32 + quad * 8);
                #pragma unroll
                for (int nt = 0; nt < 2; ++nt) {
                    f32x4 acc = {0.f, 0.f, 0.f, 0.f};
                    #pragma unroll
                    for (int kt = 0; kt < 4; ++kt)
                        acc = __builtin_amdgcn_mfma_f32_16x16x32_bf16(qwf[nt][kt], af[kt], acc, 0, 0, 0);
                    bf16x4 pk;
                    #pragma unroll
                    for (int r = 0; r < 4; ++r) pk[r] = (__bf16)((acc[r] + qb4[nt][r]) * SCALE);
                    *(bf16x4*)(buf + (m2 * 16 + l16) * 40 + nt * 16 + quad * 4) = pk;
                }
            }
            qf[half * 2 + 0] = *(const bf16x8*)(buf + l16 * 40 + quad * 8);
            qf[half * 2 + 1] = *(const bf16x8*)(buf + (16 + l16) * 40 + quad * 8);
        }
    }

    // ---- V phase: original orientation (token-major C rows give packed
    //      transposed stores) into [feat][token-half] [32][40] ----
    {
        bf16x8 vwf[2][4]; float vbb[2];
        #pragma unroll
        for (int nt = 0; nt < 2; ++nt) {
            const int ng = 256 + h * 32 + nt * 16 + l16;
            vbb[nt] = qkv_b[ng];
            #pragma unroll
            for (int kt = 0; kt < 4; ++kt)
                vwf[nt][kt] = *(const bf16x8*)(wqkv + ng * 128 + kt * 32 + quad * 8);
        }
        #pragma unroll
        for (int half = 0; half < 2; ++half) {
            #pragma unroll
            for (int m2 = 0; m2 < 2; ++m2) {
                const int mt = half * 2 + m2;
                bf16x8 af[4];
                #pragma unroll
                for (int kt = 0; kt < 4; ++kt)
                    af[kt] = *(const bf16x8*)(xs + (mt * 16 + l16) * 136 + kt * 32 + quad * 8);
                #pragma unroll
                for (int nt = 0; nt < 2; ++nt) {
                    f32x4 acc = {0.f, 0.f, 0.f, 0.f};
                    #pragma unroll
                    for (int kt = 0; kt < 4; ++kt)
                        acc = __builtin_amdgcn_mfma_f32_16x16x32_bf16(af[kt], vwf[nt][kt], acc, 0, 0, 0);
                    bf16x4 pk;
                    #pragma unroll
                    for (int r = 0; r < 4; ++r) pk[r] = (__bf16)(acc[r] + vbb[nt]);
                    *(bf16x4*)(buf + (nt * 16 + l16) * 40 + m2 * 16 + quad * 4) = pk;
                }
            }
            #pragma unroll
            for (int nf = 0; nf < 2; ++nf)
                vf[half][nf] = *(const bf16x8*)(buf + (nf * 16 + l16) * 40 + quad * 8);
        }
    }

    // ---- bias pointers + band-0 prefetch (global loads, no LDS dep ->
    //      issue before barrier 2 so latency hides under the barrier) ----
    const int wm = win % NWMASK;
    const float* rt = rpe_t + h * 4096;                  // [col][row]
    const float* mw = maskp + (size_t)wm * 4096;         // TB: [col][row]; else [row][col]
    f32x4 rb4[4], mb4[4];
    #pragma unroll
    for (int nt = 0; nt < 4; ++nt) {
        rb4[nt] = *(const f32x4*)(rt + (nt * 16 + l16) * 64 + quad * 4);
        if constexpr (TB)
            mb4[nt] = *(const f32x4*)(mw + (nt * 16 + l16) * 64 + quad * 4);
    }
    __syncthreads();   // barrier 2: all xs reads done -> O staging overlay safe

    // ---- attention per 16-row band: S -> exp (no max-sub) -> P (buf) ->
    //      PV + ones-MFMA row-sum -> O into xs (stride 136, aligned) ----
    bf16x8 onesf;
    #pragma unroll
    for (int j = 0; j < 8; ++j) onesf[j] = (__bf16)1.0f;

    #pragma unroll
    for (int mt = 0; mt < 4; ++mt) {
        f32x4 sc[4];
        #pragma unroll
        for (int nt = 0; nt < 4; ++nt) {
            f32x4 z = {0.f, 0.f, 0.f, 0.f};
            sc[nt] = __builtin_amdgcn_mfma_f32_16x16x32_bf16(qf[mt], kf[nt], z, 0, 0, 0);
        }
        float mbs[4][4];
        if constexpr (!TB) {   // fallback: v4-style coalesced scalar mask loads
            #pragma unroll
            for (int nt = 0; nt < 4; ++nt)
                #pragma unroll
                for (int r = 0; r < 4; ++r)
                    mbs[nt][r] = mw[(mt * 16 + quad * 4 + r) * 64 + nt * 16 + l16];
        }
        // P band (16x64): exp without max-sub, C-layout -> wave-private buf
        #pragma unroll
        for (int nt = 0; nt < 4; ++nt)
            #pragma unroll
            for (int r = 0; r < 4; ++r) {
                const float m = TB ? mb4[nt][r] : mbs[nt][r];
                buf[(quad * 4 + r) * 72 + nt * 16 + l16] =
                    (__bf16)__expf(sc[nt][r] + rb4[nt][r] + m);
            }
        // prefetch next band's biases (consumed above; PV below covers latency)
        if (mt < 3) {
            #pragma unroll
            for (int nt = 0; nt < 4; ++nt) {
                rb4[nt] = *(const f32x4*)(rt + (nt * 16 + l16) * 64 + (mt + 1) * 16 + quad * 4);
                if constexpr (TB)
                    mb4[nt] = *(const f32x4*)(mw + (nt * 16 + l16) * 64 + (mt + 1) * 16 + quad * 4);
            }
        }
        f32x4 oa[2] = {{0.f,0.f,0.f,0.f},{0.f,0.f,0.f,0.f}};
        f32x4 os = {0.f, 0.f, 0.f, 0.f};
        #pragma unroll
        for (int kt = 0; kt < 2; ++kt) {
            bf16x8 pf = *(const bf16x8*)(buf + l16 * 72 + kt * 32 + quad * 8);
            oa[0] = __builtin_amdgcn_mfma_f32_16x16x32_bf16(pf, vf[kt][0], oa[0], 0, 0, 0);
            oa[1] = __builtin_amdgcn_mfma_f32_16x16x32_bf16(pf, vf[kt][1], oa[1], 0, 0, 0);
            os    = __builtin_amdgcn_mfma_f32_16x16x32_bf16(pf, onesf,     os,    0, 0, 0);
        }
        #pragma unroll
        for (int r = 0; r < 4; ++r) {
            const float inv = 1.0f / os[r];
            const int orow = mt * 16 + quad * 4 + r;
            xs[orow * 136 + h * 32 + l16]      = (__bf16)(oa[0][r] * inv);
            xs[orow * 136 + h * 32 + 16 + l16] = (__bf16)(oa[1][r] * inv);
        }
    }
    __syncthreads();   // barrier 3: O staging (all heads) ready

    // ---- proj GEMM: wave h = token band, K=128 over 4 heads' O ----
    bf16x8 of[4];
    #pragma unroll
    for (int kt = 0; kt < 4; ++kt)
        of[kt] = *(const bf16x8*)(xs + (h * 16 + l16) * 136 + kt * 32 + quad * 8);
    #pragma unroll
    for (int nt = 0; nt < 8; ++nt) {
        const int ng = nt * 16 + l16;
        const float b = proj_b[ng];
        bf16x8 wf[4];
        #pragma unroll
        for (int kt = 0; kt < 4; ++kt)
            wf[kt] = *(const bf16x8*)(wproj + ng * 128 + kt * 32 + quad * 8);
        f32x4 acc = {0.f, 0.f, 0.f, 0.f};
        #pragma unroll
        for (int kt = 0; kt < 4; ++kt)
            acc = __builtin_amdgcn_mfma_f32_16x16x32_bf16(of[kt], wf[kt], acc, 0, 0, 0);
        float* dst = out + ((size_t)win * 64 + h * 16 + quad * 4) * 128 + ng;
        #pragma unroll
        for (int r = 0; r < 4; ++r) dst[(size_t)r * 128] = acc[r] + b;
    }
}

// ---------------- launch ----------------
extern "C" void kernel_launch(void* const* d_in, const int* in_sizes, int n_in,
                              void* d_out, int out_size, void* d_ws, size_t ws_size,
                              hipStream_t stream) {
    const float* x      = (const float*)d_in[0];
    const float* mask   = (const float*)d_in[1];
    const float* qkv_w  = (const float*)d_in[2];
    const float* qkv_b  = (const float*)d_in[3];
    const float* proj_w = (const float*)d_in[4];
    const float* proj_b = (const float*)d_in[5];
    const float* tbl    = (const float*)d_in[6];
    const int*   ridx   = (const int*)d_in[7];
    float* out = (float*)d_out;

    // ws: wqkv bf16 [384*128] | wproj bf16 [128*128] | rpe_t f32 [4][64][64]
    //     | mask_t f32 [392][64][64] (optional, 6.4MB)
    __bf16* wqkv  = (__bf16*)d_ws;
    __bf16* wproj = wqkv + 384 * 128;
    float*  rpe_t = (float*)((char*)d_ws + 131072);
    float*  mask_t = (float*)((char*)d_ws + 196608);
    const size_t need_tb = 196608 + (size_t)NWMASK * 4096 * 4;   // 6,619,136 B
    const bool tb = ws_size >= need_tb;

    prep<<<tb ? 712 : 320, 256, 0, stream>>>(qkv_w, proj_w, tbl, ridx,
                                             wqkv, wproj, rpe_t, mask, mask_t,
                                             tb ? 1 : 0);
    if (tb)
        wattn_main<true><<<3136, 256, 0, stream>>>(x, mask_t, qkv_b, proj_b,
                                                   wqkv, wproj, rpe_t, out);
    else
        wattn_main<false><<<3136, 256, 0, stream>>>(x, mask, qkv_b, proj_b,
                                                    wqkv, wproj, rpe_t, out);
}